// Round 2
// baseline (555.922 us; speedup 1.0000x reference)
//
#include <hip/hip_runtime.h>

constexpr int BATCH = 4;
constexpr int SEQ   = 512;   // TQ == TS
constexpr int DM    = 512;
constexpr int NH    = 8;
constexpr int NV    = 32000;
constexpr int NROWS = BATCH * SEQ;  // 2048

typedef short short8 __attribute__((ext_vector_type(8)));
typedef float floatx4 __attribute__((ext_vector_type(4)));
typedef float floatv4 __attribute__((ext_vector_type(4)));

// ---------------- helpers ----------------
__device__ __forceinline__ float wave_reduce_max(float v) {
#pragma unroll
  for (int o = 32; o > 0; o >>= 1) v = fmaxf(v, __shfl_down(v, o, 64));
  return v;
}
__device__ __forceinline__ float wave_reduce_sum(float v) {
#pragma unroll
  for (int o = 32; o > 0; o >>= 1) v += __shfl_down(v, o, 64);
  return v;
}
__device__ __forceinline__ unsigned short f2bf(float f) {
  unsigned u = __float_as_uint(f);
  u += 0x7FFFu + ((u >> 16) & 1u);   // RNE
  return (unsigned short)(u >> 16);
}
__device__ __forceinline__ float bf2f(unsigned short b) {
  return __uint_as_float(((unsigned)b) << 16);
}

// ---------------- fused prep: wfold | converts | map clear+build | bias fold ----------------
// block ranges: [0,64) wfold, [64,2368) converts, [2368,2372) map, [2372,2500) bias fold
__global__ __launch_bounds__(256)
void prep_kernel(const float* __restrict__ dec, const float* __restrict__ enc,
                 const float* __restrict__ Wk,
                 unsigned short* __restrict__ dec_bf, unsigned short* __restrict__ enc_bf,
                 unsigned short* __restrict__ wk_bf,
                 const int* __restrict__ src, int* __restrict__ map,
                 const float* __restrict__ Wq, const float* __restrict__ WfcQ,
                 unsigned short* __restrict__ wqc_bf,
                 const float* __restrict__ bfcQ, const float* __restrict__ bq,
                 float* __restrict__ bq2) {
  __shared__ float As[16][68];
  __shared__ float Bs[16][68];
  const int b = blockIdx.x, tid = threadIdx.x;
  if (b < 64) {
    // ---- weight fold: Wqc[m,n] = sum_k Wq[m,k]*WfcQ[k,n], bf16 out ----
    const int m0 = (b >> 3) << 6, n0 = (b & 7) << 6;
    const int tx = tid & 15, ty = tid >> 4;
    const int r = tid >> 2, c = (tid & 3) << 2;
    float acc[4][4] = {};
    for (int k0 = 0; k0 < DM; k0 += 16) {
      const float4 av = *(const float4*)(Wq + (size_t)(m0 + r) * DM + k0 + c);
      As[c + 0][r] = av.x; As[c + 1][r] = av.y; As[c + 2][r] = av.z; As[c + 3][r] = av.w;
      const float4 bv = *(const float4*)(WfcQ + (size_t)(k0 + ty) * DM + n0 + (tx << 2));
      *(float4*)(&Bs[ty][tx << 2]) = bv;
      __syncthreads();
#pragma unroll
      for (int kk = 0; kk < 16; ++kk) {
        const float4 a4 = *(const float4*)(&As[kk][ty << 2]);
        const float4 b4 = *(const float4*)(&Bs[kk][tx << 2]);
        const float a[4] = {a4.x, a4.y, a4.z, a4.w};
        const float bb[4] = {b4.x, b4.y, b4.z, b4.w};
#pragma unroll
        for (int i = 0; i < 4; ++i)
#pragma unroll
          for (int j = 0; j < 4; ++j) acc[i][j] = fmaf(a[i], bb[j], acc[i][j]);
      }
      __syncthreads();
    }
#pragma unroll
    for (int i = 0; i < 4; ++i)
#pragma unroll
      for (int j = 0; j < 4; ++j)
        wqc_bf[(size_t)(m0 + (ty << 2) + i) * DM + n0 + (tx << 2) + j] = f2bf(acc[i][j]);
  } else if (b < 2368) {
    // ---- fp32 -> bf16 converts (dec / enc / Wk) ----
    const int cb = b - 64;
    const float* in; unsigned short* outp; int i;
    if (cb < 1024)      { in = dec; outp = dec_bf; i = cb * 256 + tid; }
    else if (cb < 2048) { in = enc; outp = enc_bf; i = (cb - 1024) * 256 + tid; }
    else                { in = Wk;  outp = wk_bf;  i = (cb - 2048) * 256 + tid; }
    const float4 v = ((const float4*)in)[i];
    ushort4 o;
    o.x = f2bf(v.x); o.y = f2bf(v.y); o.z = f2bf(v.z); o.w = f2bf(v.w);
    ((ushort4*)outp)[i] = o;
  } else if (b < 2372) {
    // ---- dedup map: clear our batch's region, then map[b][v] = some ts with src[b][ts]==v ----
    const int bb = b - 2368;
    int4* mp = (int4*)(map + (size_t)bb * NV);
    const int4 neg = make_int4(-1, -1, -1, -1);
    for (int i = tid; i < NV / 4; i += 256) mp[i] = neg;
    __syncthreads();
    const int v0 = src[bb * SEQ + tid];
    atomicCAS(&map[(size_t)bb * NV + v0], -1, tid);
    const int v1 = src[bb * SEQ + tid + 256];
    atomicCAS(&map[(size_t)bb * NV + v1], -1, tid + 256);
  } else {
    // ---- bq2[n] = bq[n] + dot(Wq[n,:], bfcQ) ----
    const int h = tid >> 6, l = tid & 63;
    const int n = (b - 2372) * 4 + h;
    float s = 0.f;
#pragma unroll
    for (int t = 0; t < 8; ++t) {
      const int j = l + 64 * t;
      s = fmaf(Wq[(size_t)n * DM + j], bfcQ[j], s);
    }
    s = wave_reduce_sum(s);
    if (l == 0) bq2[n] = bq[n] + s;
  }
}

// ---------------- bf16 MFMA GEMM: C[m,n] = A[m,:] . W[n,:] + bias[n], bf16 out ----------------
// 64x64 tile, 256 threads (4 waves), BK=64, z selects {qlin, klin}. Coalesced int4 C-store via LDS repack.
__global__ __launch_bounds__(256)
void gemm_mfma_kernel(const unsigned short* __restrict__ A0, const unsigned short* __restrict__ W0,
                      const float* __restrict__ b0, unsigned short* __restrict__ C0,
                      const unsigned short* __restrict__ A1, const unsigned short* __restrict__ W1,
                      const float* __restrict__ b1, unsigned short* __restrict__ C1) {
  const unsigned short* A; const unsigned short* W; const float* bias; unsigned short* C;
  if (blockIdx.z == 0) { A = A0; W = W0; bias = b0; C = C0; }
  else                 { A = A1; W = W1; bias = b1; C = C1; }
  const int m0 = blockIdx.y << 6, n0 = blockIdx.x << 6;
  __shared__ __align__(16) unsigned short As[64 * 72];  // row stride 72 bf16 = 144 B
  __shared__ __align__(16) unsigned short Ws[64 * 72];
  const int tid = threadIdx.x;
  const int wv = tid >> 6, l = tid & 63;
  const int lm = l & 15, lq = l >> 4;
  floatx4 acc[4] = {};
  for (int k0 = 0; k0 < DM; k0 += 64) {
#pragma unroll
    for (int i = 0; i < 2; ++i) {
      const int ch = tid + (i << 8);
      const int row = ch >> 3, c8 = (ch & 7) << 3;
      *(int4*)(&As[row * 72 + c8]) = *(const int4*)(A + (size_t)(m0 + row) * DM + k0 + c8);
      *(int4*)(&Ws[row * 72 + c8]) = *(const int4*)(W + (size_t)(n0 + row) * DM + k0 + c8);
    }
    __syncthreads();
#pragma unroll
    for (int ks = 0; ks < 64; ks += 32) {
      const short8 a = *(const short8*)(&As[(16 * wv + lm) * 72 + ks + lq * 8]);
#pragma unroll
      for (int c = 0; c < 4; ++c) {
        const short8 b = *(const short8*)(&Ws[(16 * c + lm) * 72 + ks + lq * 8]);
        acc[c] = __builtin_amdgcn_mfma_f32_16x16x32_bf16(a, b, acc[c], 0, 0, 0);
      }
    }
    __syncthreads();   // (final iteration: makes As safe to reuse as epilogue staging)
  }
  // epilogue: bias + bf16 repack into LDS, then coalesced 16B stores
#pragma unroll
  for (int c = 0; c < 4; ++c) {
    const float bv = bias[n0 + 16 * c + lm];
#pragma unroll
    for (int r = 0; r < 4; ++r)
      As[(16 * wv + lq * 4 + r) * 72 + 16 * c + lm] = f2bf(acc[c][r] + bv);
  }
  __syncthreads();
#pragma unroll
  for (int i = 0; i < 2; ++i) {
    const int idx = tid + (i << 8);
    const int row = idx >> 3, c8 = (idx & 7) << 3;
    *(int4*)(C + (size_t)(m0 + row) * DM + n0 + c8) = *(const int4*)(&As[row * 72 + c8]);
  }
}

// ---------------- fused attention: scores (fp32, in-register) + softmax + head-mean +
// scatter + exp + denom + gate. Grid (64 tq-tiles, 4 batches), 512 threads, wave h = head h.
// Each block owns 8 tq rows; MFMA M=16 with top 8 rows garbage (discarded).
__global__ __launch_bounds__(512)
void attn_kernel(const unsigned short* __restrict__ Q, const unsigned short* __restrict__ Kk,
                 const int* __restrict__ src, const int* __restrict__ map,
                 const float* __restrict__ dec, const float* __restrict__ Wfcw,
                 const float* __restrict__ bfcw,
                 float* __restrict__ expa, float* __restrict__ row_a,
                 float* __restrict__ row_b) {
  __shared__ float amean[8][520];   // head-mean accum; later reused to hold exp values
  __shared__ float aslot[8][512];   // dedup scatter slots
  const int bb = blockIdx.y, tq0 = blockIdx.x << 3;
  const int tid = threadIdx.x, h = tid >> 6, l = tid & 63;
  const int lm = l & 15, lq = l >> 4;
  for (int i = tid; i < 8 * 520; i += 512) ((float*)amean)[i] = 0.f;
  for (int i = tid; i < 8 * 512; i += 512) ((float*)aslot)[i] = 0.f;
  __syncthreads();

  // ---- QK^T for head h: A-frag rows = tq0+lm (lm>=8 garbage-but-safe), B rows = ts tiles ----
  const size_t qrow = (size_t)(bb * SEQ + tq0 + lm) * DM + h * 64 + lq * 8;
  const short8 qa0 = *(const short8*)(Q + qrow);
  const short8 qa1 = *(const short8*)(Q + qrow + 32);
  const unsigned short* kbase = Kk + (size_t)(bb * SEQ + lm) * DM + h * 64 + lq * 8;
  floatx4 acc[32];
#pragma unroll
  for (int c = 0; c < 32; ++c) acc[c] = (floatx4){0.f, 0.f, 0.f, 0.f};
#pragma unroll
  for (int c = 0; c < 32; ++c) {
    const short8 kb0 = *(const short8*)(kbase + (size_t)(16 * c) * DM);
    const short8 kb1 = *(const short8*)(kbase + (size_t)(16 * c) * DM + 32);
    acc[c] = __builtin_amdgcn_mfma_f32_16x16x32_bf16(qa0, kb0, acc[c], 0, 0, 0);
    acc[c] = __builtin_amdgcn_mfma_f32_16x16x32_bf16(qa1, kb1, acc[c], 0, 0, 0);
  }

  // ---- softmax over ts for each row r (C layout: col = ts0+lm, row = lq*4+r) ----
  float mx[4] = {-3.0e38f, -3.0e38f, -3.0e38f, -3.0e38f};
#pragma unroll
  for (int c = 0; c < 32; ++c)
#pragma unroll
    for (int r = 0; r < 4; ++r) mx[r] = fmaxf(mx[r], acc[c][r]);
#pragma unroll
  for (int r = 0; r < 4; ++r)
#pragma unroll
    for (int o = 8; o > 0; o >>= 1) mx[r] = fmaxf(mx[r], __shfl_xor(mx[r], o, 64));
  float sm[4] = {0.f, 0.f, 0.f, 0.f};
#pragma unroll
  for (int c = 0; c < 32; ++c)
#pragma unroll
    for (int r = 0; r < 4; ++r) {
      const float e = __expf(0.125f * (acc[c][r] - mx[r]));
      acc[c][r] = e;
      sm[r] += e;
    }
#pragma unroll
  for (int r = 0; r < 4; ++r)
#pragma unroll
    for (int o = 8; o > 0; o >>= 1) sm[r] += __shfl_xor(sm[r], o, 64);
  // head-mean accumulate (valid rows are 0..7 <=> lq < 2); fold 1/8 into the prob scale
  if (lq < 2) {
#pragma unroll
    for (int r = 0; r < 4; ++r) {
      const float inv = 0.125f / sm[r];
      const int row = lq * 4 + r;
#pragma unroll
      for (int c = 0; c < 32; ++c)
        atomicAdd(&amean[row][16 * c + lm], acc[c][r] * inv);
    }
  }
  __syncthreads();

  // ---- dedup scatter: thread t = ts; rep slot collects total mass per distinct token ----
  const int sv = src[bb * SEQ + tid];
  const int rep = map[(size_t)bb * NV + sv];
#pragma unroll
  for (int r = 0; r < 8; ++r) atomicAdd(&aslot[r][rep], amean[r][tid]);
  __syncthreads();

  // ---- exp, expa rows, reuse amean to stage exp values for the denom reduce ----
#pragma unroll
  for (int r = 0; r < 8; ++r) {
    const float ev = __expf(aslot[r][tid]);
    expa[(size_t)(bb * SEQ + tq0 + r) * SEQ + tid] = ev;
    amean[r][tid] = ev;
  }
  __syncthreads();

  // ---- wave h reduces row h: exp-sum denom and gate dot ----
  const int grow = bb * SEQ + tq0 + h;
  float es = 0.f, ds = 0.f;
#pragma unroll
  for (int t = 0; t < 8; ++t) {
    const int j = l + 64 * t;
    es += amean[h][j];
    ds = fmaf(dec[(size_t)grow * DM + j], Wfcw[j], ds);
  }
  es = wave_reduce_sum(es);
  ds = wave_reduce_sum(ds);
  if (l == 0) {
    const float w = 1.f / (1.f + __expf(-(ds + bfcw[0])));
    row_a[grow] = 1.f - w;
    row_b[grow] = w / ((float)(NV - SEQ) + es);
  }
}

// ---------------- out = (1-w)*p1 + (w/denom)*e, 2D grid, nontemporal stream ----------------
__global__ __launch_bounds__(320)
void final_kernel(const float* __restrict__ p1, const int* __restrict__ map,
                  const float* __restrict__ expa, const float* __restrict__ row_a,
                  const float* __restrict__ row_b, float* __restrict__ out) {
  const int row = blockIdx.y;                       // 0..2047 (uniform per block)
  const int q4  = blockIdx.x * 320 + threadIdx.x;   // 0..7999 (25*320 == NV/4 exactly)
  const int bb  = row >> 9;
  const size_t g = (size_t)row * (NV / 4) + q4;
  const floatv4 p = __builtin_nontemporal_load((const floatv4*)p1 + g);
  const int4 m = *(const int4*)(map + (size_t)bb * NV + (q4 << 2));
  const float ra = row_a[row], rb = row_b[row];
  const float* ea = expa + (size_t)row * SEQ;
  // branchless: unconditional clamped gather (expa row is 2KB, L1-resident), then select
  const float t0 = ea[m.x & 511];
  const float t1 = ea[m.y & 511];
  const float t2 = ea[m.z & 511];
  const float t3 = ea[m.w & 511];
  const float e0 = (m.x >= 0) ? t0 : 1.f;
  const float e1 = (m.y >= 0) ? t1 : 1.f;
  const float e2 = (m.z >= 0) ? t2 : 1.f;
  const float e3 = (m.w >= 0) ? t3 : 1.f;
  floatv4 o;
  o.x = fmaf(ra, p.x, rb * e0);
  o.y = fmaf(ra, p.y, rb * e1);
  o.z = fmaf(ra, p.z, rb * e2);
  o.w = fmaf(ra, p.w, rb * e3);
  __builtin_nontemporal_store(o, (floatv4*)out + g);
}

extern "C" void kernel_launch(void* const* d_in, const int* in_sizes, int n_in,
                              void* d_out, int out_size, void* d_ws, size_t ws_size,
                              hipStream_t stream) {
  const float* dec  = (const float*)d_in[1];
  const float* enc  = (const float*)d_in[2];
  const int*   src  = (const int*)d_in[3];
  const float* p1   = (const float*)d_in[4];
  const float* WfcQ = (const float*)d_in[5];
  const float* bfcQ = (const float*)d_in[6];
  const float* Wq   = (const float*)d_in[7];
  const float* bq   = (const float*)d_in[8];
  const float* Wk   = (const float*)d_in[9];
  const float* bk   = (const float*)d_in[10];
  const float* Wfcw = (const float*)d_in[11];
  const float* bfcw = (const float*)d_in[12];
  float* out = (float*)d_out;

  char* ws = (char*)d_ws;
  int*            map     = (int*)(ws);                                   // 512 KB
  unsigned short* dec_bf  = (unsigned short*)(ws + (size_t)( 1 << 20));   // 2 MB
  unsigned short* enc_bf  = (unsigned short*)(ws + (size_t)( 3 << 20));   // 2 MB
  unsigned short* wk_bf   = (unsigned short*)(ws + (size_t)( 5 << 20));   // 512 KB
  unsigned short* wqc_bf  = (unsigned short*)(ws + (size_t)( 5 << 20) + (512 << 10));
  float*          bq2     = (float*)(ws + (size_t)( 6 << 20));            // 2 KB
  float*          row_a   = (float*)(ws + (size_t)( 6 << 20) + (64 << 10));
  float*          row_b   = (float*)(ws + (size_t)( 6 << 20) + (128 << 10));
  unsigned short* qlin_bf = (unsigned short*)(ws + (size_t)( 7 << 20));   // 2 MB
  unsigned short* klin_bf = (unsigned short*)(ws + (size_t)( 9 << 20));   // 2 MB
  float*          expa    = (float*)(ws + (size_t)(11 << 20));            // 4 MB

  prep_kernel<<<2500, 256, 0, stream>>>(dec, enc, Wk, dec_bf, enc_bf, wk_bf,
                                        src, map, Wq, WfcQ, wqc_bf, bfcQ, bq, bq2);

  gemm_mfma_kernel<<<dim3(8, 32, 2), 256, 0, stream>>>(
      dec_bf, wqc_bf, bq2, qlin_bf, enc_bf, wk_bf, bk, klin_bf);

  attn_kernel<<<dim3(64, BATCH), 512, 0, stream>>>(qlin_bf, klin_bf, src, map, dec,
                                                   Wfcw, bfcw, expa, row_a, row_b);

  final_kernel<<<dim3(25, NROWS), 320, 0, stream>>>(p1, map, expa, row_a, row_b, out);
}

// Round 3
// 507.438 us; speedup vs baseline: 1.0955x; 1.0955x over previous
//
#include <hip/hip_runtime.h>

constexpr int BATCH = 4;
constexpr int SEQ   = 512;   // TQ == TS
constexpr int DM    = 512;
constexpr int NH    = 8;
constexpr int NV    = 32000;
constexpr int NROWS = BATCH * SEQ;  // 2048

typedef short short8 __attribute__((ext_vector_type(8)));
typedef float floatx4 __attribute__((ext_vector_type(4)));
typedef float floatv4 __attribute__((ext_vector_type(4)));

// ---------------- helpers ----------------
__device__ __forceinline__ float wave_reduce_max(float v) {
#pragma unroll
  for (int o = 32; o > 0; o >>= 1) v = fmaxf(v, __shfl_down(v, o, 64));
  return v;
}
__device__ __forceinline__ float wave_reduce_sum(float v) {
#pragma unroll
  for (int o = 32; o > 0; o >>= 1) v += __shfl_down(v, o, 64);
  return v;
}
__device__ __forceinline__ unsigned short f2bf(float f) {
  unsigned u = __float_as_uint(f);
  u += 0x7FFFu + ((u >> 16) & 1u);   // RNE
  return (unsigned short)(u >> 16);
}
__device__ __forceinline__ float bf2f(unsigned short b) {
  return __uint_as_float(((unsigned)b) << 16);
}

// ---------------- fused prep: wfold | converts(+gate dot) | map clear+build | bias fold ------
// block ranges: [0,64) wfold, [64,2368) converts, [2368,2372) map, [2372,2500) bias fold
__global__ __launch_bounds__(256)
void prep_kernel(const float* __restrict__ dec, const float* __restrict__ enc,
                 const float* __restrict__ Wk,
                 unsigned short* __restrict__ dec_bf, unsigned short* __restrict__ enc_bf,
                 unsigned short* __restrict__ wk_bf,
                 const int* __restrict__ src, int* __restrict__ map,
                 const float* __restrict__ Wq, const float* __restrict__ WfcQ,
                 unsigned short* __restrict__ wqc_bf,
                 const float* __restrict__ bfcQ, const float* __restrict__ bq,
                 float* __restrict__ bq2,
                 const float* __restrict__ Wfcw, float* __restrict__ gate_d) {
  __shared__ float As[16][68];
  __shared__ float Bs[16][68];
  __shared__ float gsum[2];
  const int b = blockIdx.x, tid = threadIdx.x;
  if (b < 64) {
    // ---- weight fold: Wqc[m,n] = sum_k Wq[m,k]*WfcQ[k,n], bf16 out ----
    const int m0 = (b >> 3) << 6, n0 = (b & 7) << 6;
    const int tx = tid & 15, ty = tid >> 4;
    const int r = tid >> 2, c = (tid & 3) << 2;
    float acc[4][4] = {};
    for (int k0 = 0; k0 < DM; k0 += 16) {
      const float4 av = *(const float4*)(Wq + (size_t)(m0 + r) * DM + k0 + c);
      As[c + 0][r] = av.x; As[c + 1][r] = av.y; As[c + 2][r] = av.z; As[c + 3][r] = av.w;
      const float4 bv = *(const float4*)(WfcQ + (size_t)(k0 + ty) * DM + n0 + (tx << 2));
      *(float4*)(&Bs[ty][tx << 2]) = bv;
      __syncthreads();
#pragma unroll
      for (int kk = 0; kk < 16; ++kk) {
        const float4 a4 = *(const float4*)(&As[kk][ty << 2]);
        const float4 b4 = *(const float4*)(&Bs[kk][tx << 2]);
        const float a[4] = {a4.x, a4.y, a4.z, a4.w};
        const float bb[4] = {b4.x, b4.y, b4.z, b4.w};
#pragma unroll
        for (int i = 0; i < 4; ++i)
#pragma unroll
          for (int j = 0; j < 4; ++j) acc[i][j] = fmaf(a[i], bb[j], acc[i][j]);
      }
      __syncthreads();
    }
#pragma unroll
    for (int i = 0; i < 4; ++i)
#pragma unroll
      for (int j = 0; j < 4; ++j)
        wqc_bf[(size_t)(m0 + (ty << 2) + i) * DM + n0 + (tx << 2) + j] = f2bf(acc[i][j]);
  } else if (b < 2368) {
    const int cb = b - 64;
    if (cb < 1024) {
      // ---- dec convert + per-row gate dot (block covers dec rows 2cb, 2cb+1) ----
      if (tid < 2) gsum[tid] = 0.f;
      __syncthreads();
      const int i = cb * 256 + tid;
      const float4 v = ((const float4*)dec)[i];
      ushort4 o;
      o.x = f2bf(v.x); o.y = f2bf(v.y); o.z = f2bf(v.z); o.w = f2bf(v.w);
      ((ushort4*)dec_bf)[i] = o;
      const int col = (tid & 127) << 2;
      const float4 wv = *(const float4*)(Wfcw + col);
      float s = v.x * wv.x + v.y * wv.y + v.z * wv.z + v.w * wv.w;
      s = wave_reduce_sum(s);
      if ((tid & 63) == 0) atomicAdd(&gsum[tid >> 7], s);
      __syncthreads();
      if (tid == 0) { gate_d[2 * cb] = gsum[0]; gate_d[2 * cb + 1] = gsum[1]; }
    } else {
      // ---- enc / Wk converts ----
      const float* in; unsigned short* outp; int i;
      if (cb < 2048) { in = enc; outp = enc_bf; i = (cb - 1024) * 256 + tid; }
      else           { in = Wk;  outp = wk_bf;  i = (cb - 2048) * 256 + tid; }
      const float4 v = ((const float4*)in)[i];
      ushort4 o;
      o.x = f2bf(v.x); o.y = f2bf(v.y); o.z = f2bf(v.z); o.w = f2bf(v.w);
      ((ushort4*)outp)[i] = o;
    }
  } else if (b < 2372) {
    // ---- dedup map: clear our batch's region, then map[b][v] = some ts with src[b][ts]==v ----
    const int bb = b - 2368;
    int4* mp = (int4*)(map + (size_t)bb * NV);
    const int4 neg = make_int4(-1, -1, -1, -1);
    for (int i = tid; i < NV / 4; i += 256) mp[i] = neg;
    __syncthreads();
    const int v0 = src[bb * SEQ + tid];
    atomicCAS(&map[(size_t)bb * NV + v0], -1, tid);
    const int v1 = src[bb * SEQ + tid + 256];
    atomicCAS(&map[(size_t)bb * NV + v1], -1, tid + 256);
  } else {
    // ---- bq2[n] = bq[n] + dot(Wq[n,:], bfcQ) ----
    const int h = tid >> 6, l = tid & 63;
    const int n = (b - 2372) * 4 + h;
    float s = 0.f;
#pragma unroll
    for (int t = 0; t < 8; ++t) {
      const int j = l + 64 * t;
      s = fmaf(Wq[(size_t)n * DM + j], bfcQ[j], s);
    }
    s = wave_reduce_sum(s);
    if (l == 0) bq2[n] = bq[n] + s;
  }
}

// ---------------- bf16 MFMA GEMM: C[m,n] = A[m,:] . W[n,:] + bias[n], bf16 out ----------------
// 64x64 tile, 256 threads (4 waves), BK=64, z selects {qlin, klin}. Coalesced int4 C-store via LDS repack.
__global__ __launch_bounds__(256)
void gemm_mfma_kernel(const unsigned short* __restrict__ A0, const unsigned short* __restrict__ W0,
                      const float* __restrict__ b0, unsigned short* __restrict__ C0,
                      const unsigned short* __restrict__ A1, const unsigned short* __restrict__ W1,
                      const float* __restrict__ b1, unsigned short* __restrict__ C1) {
  const unsigned short* A; const unsigned short* W; const float* bias; unsigned short* C;
  if (blockIdx.z == 0) { A = A0; W = W0; bias = b0; C = C0; }
  else                 { A = A1; W = W1; bias = b1; C = C1; }
  const int m0 = blockIdx.y << 6, n0 = blockIdx.x << 6;
  __shared__ __align__(16) unsigned short As[64 * 72];  // row stride 72 bf16 = 144 B
  __shared__ __align__(16) unsigned short Ws[64 * 72];
  const int tid = threadIdx.x;
  const int wv = tid >> 6, l = tid & 63;
  const int lm = l & 15, lq = l >> 4;
  floatx4 acc[4] = {};
  for (int k0 = 0; k0 < DM; k0 += 64) {
#pragma unroll
    for (int i = 0; i < 2; ++i) {
      const int ch = tid + (i << 8);
      const int row = ch >> 3, c8 = (ch & 7) << 3;
      *(int4*)(&As[row * 72 + c8]) = *(const int4*)(A + (size_t)(m0 + row) * DM + k0 + c8);
      *(int4*)(&Ws[row * 72 + c8]) = *(const int4*)(W + (size_t)(n0 + row) * DM + k0 + c8);
    }
    __syncthreads();
#pragma unroll
    for (int ks = 0; ks < 64; ks += 32) {
      const short8 a = *(const short8*)(&As[(16 * wv + lm) * 72 + ks + lq * 8]);
#pragma unroll
      for (int c = 0; c < 4; ++c) {
        const short8 b = *(const short8*)(&Ws[(16 * c + lm) * 72 + ks + lq * 8]);
        acc[c] = __builtin_amdgcn_mfma_f32_16x16x32_bf16(a, b, acc[c], 0, 0, 0);
      }
    }
    __syncthreads();   // (final iteration: makes As safe to reuse as epilogue staging)
  }
  // epilogue: bias + bf16 repack into LDS, then coalesced 16B stores
#pragma unroll
  for (int c = 0; c < 4; ++c) {
    const float bv = bias[n0 + 16 * c + lm];
#pragma unroll
    for (int r = 0; r < 4; ++r)
      As[(16 * wv + lq * 4 + r) * 72 + 16 * c + lm] = f2bf(acc[c][r] + bv);
  }
  __syncthreads();
#pragma unroll
  for (int i = 0; i < 2; ++i) {
    const int idx = tid + (i << 8);
    const int row = idx >> 3, c8 = (idx & 7) << 3;
    *(int4*)(C + (size_t)(m0 + row) * DM + n0 + c8) = *(const int4*)(&As[row * 72 + c8]);
  }
}

// ---------------- scores[b,h,tq,ts] = 0.125 * Q_h . K_h  (bf16 MFMA, coalesced bf16 out) ------
__global__ __launch_bounds__(256)
void scores_mfma_kernel(const unsigned short* __restrict__ Q, const unsigned short* __restrict__ Kk,
                        unsigned short* __restrict__ scores) {
  const int bh = blockIdx.z, bb = bh >> 3, h = bh & 7;
  const int tq0 = blockIdx.y << 6, ts0 = blockIdx.x << 6;
  __shared__ __align__(16) unsigned short Qs[64 * 72];
  __shared__ __align__(16) unsigned short Ks[64 * 72];
  const int tid = threadIdx.x;
  const int wv = tid >> 6, l = tid & 63;
  const int lm = l & 15, lq = l >> 4;
#pragma unroll
  for (int i = 0; i < 2; ++i) {
    const int ch = tid + (i << 8);
    const int row = ch >> 3, c8 = (ch & 7) << 3;
    *(int4*)(&Qs[row * 72 + c8]) =
        *(const int4*)(Q + (size_t)(bb * SEQ + tq0 + row) * DM + h * 64 + c8);
    *(int4*)(&Ks[row * 72 + c8]) =
        *(const int4*)(Kk + (size_t)(bb * SEQ + ts0 + row) * DM + h * 64 + c8);
  }
  __syncthreads();
  floatx4 acc[4] = {};
#pragma unroll
  for (int ks = 0; ks < 64; ks += 32) {
    const short8 a = *(const short8*)(&Qs[(16 * wv + lm) * 72 + ks + lq * 8]);
#pragma unroll
    for (int c = 0; c < 4; ++c) {
      const short8 b = *(const short8*)(&Ks[(16 * c + lm) * 72 + ks + lq * 8]);
      acc[c] = __builtin_amdgcn_mfma_f32_16x16x32_bf16(a, b, acc[c], 0, 0, 0);
    }
  }
  __syncthreads();   // all LDS reads done; reuse Qs as output staging
#pragma unroll
  for (int c = 0; c < 4; ++c)
#pragma unroll
    for (int r = 0; r < 4; ++r)
      Qs[(16 * wv + lq * 4 + r) * 72 + 16 * c + lm] = f2bf(acc[c][r] * 0.125f);
  __syncthreads();
#pragma unroll
  for (int i = 0; i < 2; ++i) {
    const int idx = tid + (i << 8);
    const int row = idx >> 3, c8 = (idx & 7) << 3;
    *(int4*)(scores + ((size_t)bh * SEQ + tq0 + row) * SEQ + ts0 + c8) =
        *(const int4*)(&Qs[row * 72 + c8]);
  }
}

// ---------------- fused: per-(b,tq) softmax(8 heads) + mean + scatter + exp + denom + gate ----
// block = 512 threads (8 waves, one per head). Gate dot precomputed in prep (gate_d).
__global__ __launch_bounds__(512)
void softmax_fused_kernel(const unsigned short* __restrict__ scores, const int* __restrict__ src,
                          const int* __restrict__ map, const float* __restrict__ gate_d,
                          const float* __restrict__ bfcw,
                          float* __restrict__ expa, float* __restrict__ row_a,
                          float* __restrict__ row_b) {
  __shared__ float hp[8 * 520];
  __shared__ float aslot[512];
  __shared__ float r1[8];
  const int row = blockIdx.x, bb = row >> 9, tq = row & 511;
  const int tid = threadIdx.x, h = tid >> 6, l = tid & 63;
  aslot[tid] = 0.f;
  // wave h: softmax over ts for head h; lane l owns ts = 8l..8l+7
  const unsigned short* srow = scores + ((size_t)(bb * NH + h) * SEQ + tq) * SEQ;
  union { int4 v; unsigned short u[8]; } U;
  U.v = *(const int4*)(srow + 8 * l);
  float s[8];
#pragma unroll
  for (int i = 0; i < 8; ++i) s[i] = bf2f(U.u[i]);
  float m = s[0];
#pragma unroll
  for (int i = 1; i < 8; ++i) m = fmaxf(m, s[i]);
  m = wave_reduce_max(m);
  m = __shfl(m, 0, 64);
  float e[8], sum = 0.f;
#pragma unroll
  for (int i = 0; i < 8; ++i) { e[i] = __expf(s[i] - m); sum += e[i]; }
  sum = wave_reduce_sum(sum);
  sum = __shfl(sum, 0, 64);
  const float inv = 1.f / sum;
  float4 p0, p1v;
  p0.x = e[0] * inv; p0.y = e[1] * inv; p0.z = e[2] * inv; p0.w = e[3] * inv;
  p1v.x = e[4] * inv; p1v.y = e[5] * inv; p1v.z = e[6] * inv; p1v.w = e[7] * inv;
  *(float4*)(&hp[h * 520 + 8 * l])     = p0;
  *(float4*)(&hp[h * 520 + 8 * l + 4]) = p1v;
  __syncthreads();
  // thread t owns ts = t: head-mean, scatter to dedup slot in LDS
  float a = 0.f;
#pragma unroll
  for (int h2 = 0; h2 < 8; ++h2) a += hp[h2 * 520 + tid];
  a *= 0.125f;
  const int sv = src[bb * SEQ + tid];
  const int rep = map[(size_t)bb * NV + sv];
  atomicAdd(&aslot[rep], a);
  __syncthreads();
  // exp, write expa row, reduce denom
  const float ev = __expf(aslot[tid]);
  expa[(size_t)row * SEQ + tid] = ev;
  float es = wave_reduce_sum(ev);
  if (l == 0) r1[h] = es;
  __syncthreads();
  if (tid == 0) {
    float esum = 0.f;
#pragma unroll
    for (int i = 0; i < 8; ++i) esum += r1[i];
    const float w = 1.f / (1.f + __expf(-(gate_d[row] + bfcw[0])));
    row_a[row] = 1.f - w;
    row_b[row] = w / ((float)(NV - SEQ) + esum);
  }
}

// ---------------- out = (1-w)*p1 + (w/denom)*e, 2D grid, nontemporal stream ----------------
__global__ __launch_bounds__(320)
void final_kernel(const float* __restrict__ p1, const int* __restrict__ map,
                  const float* __restrict__ expa, const float* __restrict__ row_a,
                  const float* __restrict__ row_b, float* __restrict__ out) {
  const int row = blockIdx.y;                       // 0..2047 (uniform per block)
  const int q4  = blockIdx.x * 320 + threadIdx.x;   // 0..7999 (25*320 == NV/4 exactly)
  const int bb  = row >> 9;
  const size_t g = (size_t)row * (NV / 4) + q4;
  const floatv4 p = __builtin_nontemporal_load((const floatv4*)p1 + g);
  const int4 m = *(const int4*)(map + (size_t)bb * NV + (q4 << 2));
  const float ra = row_a[row], rb = row_b[row];
  const float* ea = expa + (size_t)row * SEQ;
  // branchless: unconditional clamped gather (expa row is 2KB, L1-resident), then select
  const float t0 = ea[m.x & 511];
  const float t1 = ea[m.y & 511];
  const float t2 = ea[m.z & 511];
  const float t3 = ea[m.w & 511];
  const float e0 = (m.x >= 0) ? t0 : 1.f;
  const float e1 = (m.y >= 0) ? t1 : 1.f;
  const float e2 = (m.z >= 0) ? t2 : 1.f;
  const float e3 = (m.w >= 0) ? t3 : 1.f;
  floatv4 o;
  o.x = fmaf(ra, p.x, rb * e0);
  o.y = fmaf(ra, p.y, rb * e1);
  o.z = fmaf(ra, p.z, rb * e2);
  o.w = fmaf(ra, p.w, rb * e3);
  __builtin_nontemporal_store(o, (floatv4*)out + g);
}

extern "C" void kernel_launch(void* const* d_in, const int* in_sizes, int n_in,
                              void* d_out, int out_size, void* d_ws, size_t ws_size,
                              hipStream_t stream) {
  const float* dec  = (const float*)d_in[1];
  const float* enc  = (const float*)d_in[2];
  const int*   src  = (const int*)d_in[3];
  const float* p1   = (const float*)d_in[4];
  const float* WfcQ = (const float*)d_in[5];
  const float* bfcQ = (const float*)d_in[6];
  const float* Wq   = (const float*)d_in[7];
  const float* bq   = (const float*)d_in[8];
  const float* Wk   = (const float*)d_in[9];
  const float* bk   = (const float*)d_in[10];
  const float* Wfcw = (const float*)d_in[11];
  const float* bfcw = (const float*)d_in[12];
  float* out = (float*)d_out;

  char* ws = (char*)d_ws;
  int*            map     = (int*)(ws);                                   // 512 KB
  unsigned short* dec_bf  = (unsigned short*)(ws + (size_t)( 1 << 20));   // 2 MB
  unsigned short* enc_bf  = (unsigned short*)(ws + (size_t)( 3 << 20));   // 2 MB
  unsigned short* wk_bf   = (unsigned short*)(ws + (size_t)( 5 << 20));   // 512 KB
  unsigned short* wqc_bf  = (unsigned short*)(ws + (size_t)( 5 << 20) + (512 << 10));
  float*          bq2     = (float*)(ws + (size_t)( 6 << 20));            // 2 KB
  float*          row_a   = (float*)(ws + (size_t)( 6 << 20) + (64 << 10));
  float*          row_b   = (float*)(ws + (size_t)( 6 << 20) + (128 << 10));
  float*          gate_d  = (float*)(ws + (size_t)( 6 << 20) + (192 << 10));  // 8 KB
  unsigned short* qlin_bf = (unsigned short*)(ws + (size_t)( 7 << 20));   // 2 MB
  unsigned short* klin_bf = (unsigned short*)(ws + (size_t)( 9 << 20));   // 2 MB
  float*          expa    = (float*)(ws + (size_t)(11 << 20));            // 4 MB
  unsigned short* scores  = (unsigned short*)(ws + (size_t)(16 << 20));   // 16.8 MB

  prep_kernel<<<2500, 256, 0, stream>>>(dec, enc, Wk, dec_bf, enc_bf, wk_bf,
                                        src, map, Wq, WfcQ, wqc_bf, bfcQ, bq, bq2,
                                        Wfcw, gate_d);

  gemm_mfma_kernel<<<dim3(8, 32, 2), 256, 0, stream>>>(
      dec_bf, wqc_bf, bq2, qlin_bf, enc_bf, wk_bf, bk, klin_bf);

  scores_mfma_kernel<<<dim3(8, 8, 32), 256, 0, stream>>>(qlin_bf, klin_bf, scores);

  softmax_fused_kernel<<<NROWS, 512, 0, stream>>>(scores, src, map, gate_d, bfcw,
                                                  expa, row_a, row_b);

  final_kernel<<<dim3(25, NROWS), 320, 0, stream>>>(p1, map, expa, row_a, row_b, out);
}